// Round 2
// baseline (216.276 us; speedup 1.0000x reference)
//
#include <hip/hip_runtime.h>

// Problem constants (B=4, N=4096, F=64)
#define NB 4
#define NN 4096
#define NF 64

typedef __attribute__((ext_vector_type(8))) short bf16x8;   // 8 bf16 in 4 VGPRs (MFMA A/B frag)
typedef __attribute__((ext_vector_type(4))) float f32x4;    // MFMA C/D frag

union S8 { unsigned short u[8]; bf16x8 v; };

// f32 -> bf16 round-to-nearest-even
__device__ __forceinline__ unsigned short f2bf(float x) {
    unsigned int uu = __builtin_bit_cast(unsigned int, x);
    uu += 0x7fffu + ((uu >> 16) & 1u);
    return (unsigned short)(uu >> 16);
}

// ---------------------------------------------------------------------------
// Pre-pass A: Q,K f32 [B,N,64,2] -> frag-major bf16 chunks
// Layout: XF[b][rg(256)][c(2)][ch(2)] = 1KB chunk; within chunk lane l holds
// 8 bf16 = X_ch[16*rg + (l&15)][c*32 + 8*(l>>4) + e], e=0..7
// ---------------------------------------------------------------------------
__global__ void prep_qk(const float* __restrict__ Q, const float* __restrict__ K,
                        short* __restrict__ QF, short* __restrict__ KF) {
    int tid = blockIdx.x * 256 + threadIdx.x;     // 262144 threads
    int sel = tid >> 17;
    int r   = tid & 0x1FFFF;
    int l  = r & 63;
    int c  = (r >> 6) & 1;
    int rg = (r >> 7) & 255;
    int b  = r >> 15;
    const float* src = sel ? K : Q;
    short*       dst = sel ? KF : QF;

    int row = rg * 16 + (l & 15);
    int k0  = c * 32 + (l >> 4) * 8;
    const float4* s4 = (const float4*)src;
    int base4 = (b * NN + row) * 32 + (k0 >> 1);  // float4 = (re,im,re,im) for k,k+1

    S8 ar, ai;
    #pragma unroll
    for (int m = 0; m < 4; ++m) {
        float4 f = s4[base4 + m];
        ar.u[2 * m]     = f2bf(f.x);
        ar.u[2 * m + 1] = f2bf(f.z);
        ai.u[2 * m]     = f2bf(f.y);
        ai.u[2 * m + 1] = f2bf(f.w);
    }
    int cid0 = ((b * 256 + rg) * 2 + c) * 2;
    *(bf16x8*)(dst + (cid0 + 0) * 512 + l * 8) = ar.v;
    *(bf16x8*)(dst + (cid0 + 1) * 512 + l * 8) = ai.v;
}

// ---------------------------------------------------------------------------
// Pre-pass B: V f32 -> frag-major (B-operand for PV: lane l holds
// V_ch[j = jt*64 + c*32 + 8*(l>>4)+e][f = ft*16 + (l&15)])
// Layout: VF[b][jt(64)][ft(4)][c(2)][ch(2)] 1KB chunks
// ---------------------------------------------------------------------------
__global__ void prep_v(const float* __restrict__ V, short* __restrict__ VF) {
    int r = blockIdx.x * 256 + threadIdx.x;       // 131072 threads
    int l  = r & 63;
    int c  = (r >> 6) & 1;
    int ft = (r >> 7) & 3;
    int jt = (r >> 9) & 63;
    int b  = (r >> 15) & 3;

    int f  = ft * 16 + (l & 15);
    int j0 = jt * 64 + c * 32 + (l >> 4) * 8;
    const float2* s2 = (const float2*)V;

    S8 ar, ai;
    #pragma unroll
    for (int e = 0; e < 8; ++e) {
        float2 g = s2[(b * NN + j0 + e) * 64 + f];
        ar.u[e] = f2bf(g.x);
        ai.u[e] = f2bf(g.y);
    }
    int cid0 = (((b * 64 + jt) * 4 + ft) * 2 + c) * 2;
    *(bf16x8*)(VF + (cid0 + 0) * 512 + l * 8) = ar.v;
    *(bf16x8*)(VF + (cid0 + 1) * 512 + l * 8) = ai.v;
}

// ---------------------------------------------------------------------------
// Pre-pass C: W_att f32 [64][64] -> frag-major (B-operand of epilogue:
// lane l holds W_att[f = ft*16 + (l&15)][g = c*32 + 8*(l>>4)+e])
// Layout: WF[ft(4)][c(2)] 1KB chunks
// ---------------------------------------------------------------------------
__global__ void prep_w(const float* __restrict__ W, short* __restrict__ WF) {
    int r = blockIdx.x * 256 + threadIdx.x;
    if (r >= 512) return;
    int l  = r & 63;
    int c  = (r >> 6) & 1;
    int ft = r >> 7;
    int row = ft * 16 + (l & 15);
    int k0  = c * 32 + (l >> 4) * 8;
    const float* sp = W + row * 64 + k0;
    S8 a;
    #pragma unroll
    for (int e = 0; e < 8; ++e) a.u[e] = f2bf(sp[e]);
    *(bf16x8*)(WF + ((ft * 2 + c) * 64 + l) * 8) = a.v;
}

// ---------------------------------------------------------------------------
// Main kernel. 512 blocks x 256 threads (4 waves). Block = (b, it, split).
// Wave w owns 16 query rows (i = it*64 + w*16 + 0..15). Per j-tile (64 keys):
//   S-phase: 32 mfma (complex QK^T), scale+leaky+causal, bf16 -> wave-private
//            LDS frag buffer (no block barrier needed).
//   PV-phase: read W-frags back, 16 mfma into persistent O accumulators.
// Epilogue: O -> frag via same LDS buffer, 16 mfma with W_att frags, + b_att,
// fp32 atomicAdd into d_out (two splits accumulate; out pre-zeroed).
// ---------------------------------------------------------------------------
__global__ __launch_bounds__(256, 2)
void attn_main(const short* __restrict__ QF, const short* __restrict__ KF,
               const short* __restrict__ VF, const short* __restrict__ WF,
               const float* __restrict__ batt, float* __restrict__ out) {
    __shared__ __align__(16) unsigned short wbuf[4][2048];  // 4KB per wave

    int m  = blockIdx.x;            // 512
    int u  = m & 255;
    int b  = u >> 6;
    int vt = u & 63;
    int sp = m >> 8;                // split 0/1
    int it = sp ? (63 - vt) : vt;   // mirrored so co-resident pairs balance
    int ntiles = it + 1;
    int halfc  = (ntiles + 1) >> 1;
    int jt0 = sp ? halfc : 0;
    int jt1 = sp ? ntiles : halfc;

    int w   = threadIdx.x >> 6;
    int l   = threadIdx.x & 63;
    int r16 = l & 15;
    int lb  = l >> 4;

    const f32x4 z = {0.f, 0.f, 0.f, 0.f};
    const float SCALE = 1.0f / 64.0f;   // 1/sqrt(4096)

    // Q frags for this wave's 16 rows (persist whole kernel)
    bf16x8 qf[2][2];
    {
        int rg = it * 4 + w;
        #pragma unroll
        for (int c = 0; c < 2; ++c)
            #pragma unroll
            for (int ch = 0; ch < 2; ++ch)
                qf[c][ch] = *(const bf16x8*)(QF + (((b * 256 + rg) * 2 + c) * 2 + ch) * 512 + l * 8);
    }

    f32x4 o[4][2];
    #pragma unroll
    for (int ft = 0; ft < 4; ++ft) { o[ft][0] = z; o[ft][1] = z; }

    unsigned short* wb = wbuf[w];

    for (int jt = jt0; jt < jt1; ++jt) {
        bool diag = (jt == it);
        #pragma unroll
        for (int ct = 0; ct < 4; ++ct) {
            bf16x8 kf[2][2];
            int rg = jt * 4 + ct;
            #pragma unroll
            for (int c = 0; c < 2; ++c)
                #pragma unroll
                for (int ch = 0; ch < 2; ++ch)
                    kf[c][ch] = *(const bf16x8*)(KF + (((b * 256 + rg) * 2 + c) * 2 + ch) * 512 + l * 8);

            // sr = Qr.Kr^T - Qi.Ki^T ; si = Qr.Ki^T + Qi.Kr^T  (k = 64 -> 2 chunks)
            f32x4 t1 = __builtin_amdgcn_mfma_f32_16x16x32_bf16(qf[0][0], kf[0][0], z, 0, 0, 0);
            t1 = __builtin_amdgcn_mfma_f32_16x16x32_bf16(qf[1][0], kf[1][0], t1, 0, 0, 0);
            f32x4 t2 = __builtin_amdgcn_mfma_f32_16x16x32_bf16(qf[0][1], kf[0][1], z, 0, 0, 0);
            t2 = __builtin_amdgcn_mfma_f32_16x16x32_bf16(qf[1][1], kf[1][1], t2, 0, 0, 0);
            f32x4 si = __builtin_amdgcn_mfma_f32_16x16x32_bf16(qf[0][0], kf[0][1], z, 0, 0, 0);
            si = __builtin_amdgcn_mfma_f32_16x16x32_bf16(qf[1][0], kf[1][1], si, 0, 0, 0);
            si = __builtin_amdgcn_mfma_f32_16x16x32_bf16(qf[0][1], kf[0][0], si, 0, 0, 0);
            si = __builtin_amdgcn_mfma_f32_16x16x32_bf16(qf[1][1], kf[1][0], si, 0, 0, 0);

            // scatter w (bf16) into wave-private frag-major LDS buffer
            int cH  = ct >> 1;
            int lb2 = ((ct & 1) << 1) | (r16 >> 3);
            int e   = r16 & 7;
            int base_r = (cH * 2 + 0) * 512 + lb2 * 128 + lb * 32 + e;
            int base_i = (cH * 2 + 1) * 512 + lb2 * 128 + lb * 32 + e;
            #pragma unroll
            for (int reg = 0; reg < 4; ++reg) {
                float sr = (t1[reg] - t2[reg]) * SCALE;
                float sv = si[reg] * SCALE;
                float wr = sr >= 0.f ? sr : 0.01f * sr;
                float wi = sv >= 0.f ? sv : 0.01f * sv;
                if (diag) {
                    int ig = w * 16 + lb * 4 + reg;   // row offset in 64-tile
                    int jg = ct * 16 + r16;           // col offset in 64-tile
                    if (jg > ig) { wr = 0.f; wi = 0.f; }
                }
                wb[base_r + reg * 8] = f2bf(wr);
                wb[base_i + reg * 8] = f2bf(wi);
            }
        }
        __builtin_amdgcn_sched_barrier(0);  // wave-synchronous LDS RAW fence (DS in-order per wave)

        bf16x8 wfr[2][2];
        #pragma unroll
        for (int c = 0; c < 2; ++c)
            #pragma unroll
            for (int ch = 0; ch < 2; ++ch)
                wfr[c][ch] = *(const bf16x8*)(wb + (c * 2 + ch) * 512 + l * 8);
        __builtin_amdgcn_sched_barrier(0);

        // PV: O[i][f] += sum_j w[i][j] * V[j][f]  per channel
        #pragma unroll
        for (int ft = 0; ft < 4; ++ft) {
            #pragma unroll
            for (int ch = 0; ch < 2; ++ch) {
                int cid0 = (((b * 64 + jt) * 4 + ft) * 2) * 2 + ch;   // c=0 chunk
                bf16x8 v0 = *(const bf16x8*)(VF + cid0 * 512 + l * 8);
                bf16x8 v1 = *(const bf16x8*)(VF + (cid0 + 2) * 512 + l * 8); // c=1
                o[ft][ch] = __builtin_amdgcn_mfma_f32_16x16x32_bf16(wfr[0][ch], v0, o[ft][ch], 0, 0, 0);
                o[ft][ch] = __builtin_amdgcn_mfma_f32_16x16x32_bf16(wfr[1][ch], v1, o[ft][ch], 0, 0, 0);
            }
        }
        __builtin_amdgcn_sched_barrier(0);  // keep next tile's LDS writes after these reads
    }

    // ---- epilogue: out = O @ W_att^T + b_att, atomically accumulated ----
    __builtin_amdgcn_sched_barrier(0);
    #pragma unroll
    for (int ft = 0; ft < 4; ++ft) {        // ft plays the "ct" role (g-cols of O)
        int cH  = ft >> 1;
        int lb2 = ((ft & 1) << 1) | (r16 >> 3);
        int e   = r16 & 7;
        #pragma unroll
        for (int ch = 0; ch < 2; ++ch) {
            int base = (cH * 2 + ch) * 512 + lb2 * 128 + lb * 32 + e;
            #pragma unroll
            for (int reg = 0; reg < 4; ++reg)
                wb[base + reg * 8] = f2bf(o[ft][ch][reg]);
        }
    }
    __builtin_amdgcn_sched_barrier(0);

    bf16x8 of[2][2];
    #pragma unroll
    for (int c = 0; c < 2; ++c)
        #pragma unroll
        for (int ch = 0; ch < 2; ++ch)
            of[c][ch] = *(const bf16x8*)(wb + (c * 2 + ch) * 512 + l * 8);

    int ibase = b * NN + it * 64 + w * 16 + lb * 4;
    #pragma unroll
    for (int ft2 = 0; ft2 < 4; ++ft2) {
        bf16x8 wa0 = *(const bf16x8*)(WF + ((ft2 * 2 + 0) * 64 + l) * 8);
        bf16x8 wa1 = *(const bf16x8*)(WF + ((ft2 * 2 + 1) * 64 + l) * 8);
        float bb = (sp == 0) ? batt[ft2 * 16 + r16] : 0.f;
        #pragma unroll
        for (int ch = 0; ch < 2; ++ch) {
            f32x4 acc = __builtin_amdgcn_mfma_f32_16x16x32_bf16(of[0][ch], wa0, z, 0, 0, 0);
            acc = __builtin_amdgcn_mfma_f32_16x16x32_bf16(of[1][ch], wa1, acc, 0, 0, 0);
            #pragma unroll
            for (int reg = 0; reg < 4; ++reg) {
                int idx = ((ibase + reg) * 64 + ft2 * 16 + r16) * 2 + ch;
                atomicAdd(out + idx, acc[reg] + bb);
            }
        }
    }
}

// ---------------------------------------------------------------------------
extern "C" void kernel_launch(void* const* d_in, const int* in_sizes, int n_in,
                              void* d_out, int out_size, void* d_ws, size_t ws_size,
                              hipStream_t stream) {
    const float* Q  = (const float*)d_in[0];
    const float* K  = (const float*)d_in[1];
    const float* V  = (const float*)d_in[2];
    const float* W  = (const float*)d_in[3];
    const float* bA = (const float*)d_in[4];
    float* out = (float*)d_out;

    // workspace layout (bf16 shorts): QF | KF | VF | WF  (~12.6 MB total)
    short* QF = (short*)d_ws;
    short* KF = QF + 2097152;
    short* VF = KF + 2097152;
    short* WF = VF + 2097152;

    hipMemsetAsync(d_out, 0, (size_t)out_size * sizeof(float), stream);
    prep_qk<<<1024, 256, 0, stream>>>(Q, K, QF, KF);
    prep_v<<<512, 256, 0, stream>>>(V, VF);
    prep_w<<<2, 256, 0, stream>>>(W, WF);
    attn_main<<<512, 256, 0, stream>>>(QF, KF, VF, WF, bA, out);
}

// Round 7
// 198.270 us; speedup vs baseline: 1.0908x; 1.0908x over previous
//
#include <hip/hip_runtime.h>

// Problem constants (B=4, N=4096, F=64)
#define NB 4
#define NN 4096
#define NF 64
#define TSTEP 8            // j-tile steps per block (2080 = 260*8 per batch)
#define BLKS_PER_B 260

typedef __attribute__((ext_vector_type(8))) short bf16x8;   // 8 bf16 (MFMA A/B frag)
typedef __attribute__((ext_vector_type(4))) float f32x4;    // MFMA C/D frag

union S8 { unsigned short u[8]; bf16x8 v; };

__device__ __forceinline__ unsigned short f2bf(float x) {
    unsigned int uu = __builtin_bit_cast(unsigned int, x);
    uu += 0x7fffu + ((uu >> 16) & 1u);
    return (unsigned short)(uu >> 16);
}

// ---------------------------------------------------------------------------
// Fused pre-pass: converts Q,K,V,W_att to frag-major bf16 AND zeroes d_out.
// Unified tid space:
//   [0, 262144)            : Q/K frag conversion
//   [262144, 393216)       : V frag conversion
//   [393216, 393728)       : W_att frag conversion
//   [393728, 918016)       : zero d_out (float4 granularity)
// ---------------------------------------------------------------------------
__global__ __launch_bounds__(256)
void prep_all(const float* __restrict__ Q, const float* __restrict__ K,
              const float* __restrict__ V, const float* __restrict__ W,
              short* __restrict__ QF, short* __restrict__ KF,
              short* __restrict__ VF, short* __restrict__ WF,
              float* __restrict__ out) {
    int tid = blockIdx.x * 256 + threadIdx.x;

    if (tid < 262144) {                       // ---- Q/K frags ----
        int sel = tid >> 17;
        int r   = tid & 0x1FFFF;
        int l  = r & 63;
        int c  = (r >> 6) & 1;
        int rg = (r >> 7) & 255;
        int b  = r >> 15;
        const float* src = sel ? K : Q;
        short*       dst = sel ? KF : QF;

        int row = rg * 16 + (l & 15);
        int k0  = c * 32 + (l >> 4) * 8;
        const float4* s4 = (const float4*)src;
        int base4 = (b * NN + row) * 32 + (k0 >> 1);

        S8 ar, ai;
        #pragma unroll
        for (int m = 0; m < 4; ++m) {
            float4 f = s4[base4 + m];
            ar.u[2 * m]     = f2bf(f.x);
            ar.u[2 * m + 1] = f2bf(f.z);
            ai.u[2 * m]     = f2bf(f.y);
            ai.u[2 * m + 1] = f2bf(f.w);
        }
        int cid0 = ((b * 256 + rg) * 2 + c) * 2;
        *(bf16x8*)(dst + (cid0 + 0) * 512 + l * 8) = ar.v;
        *(bf16x8*)(dst + (cid0 + 1) * 512 + l * 8) = ai.v;
    } else if (tid < 393216) {                // ---- V frags ----
        int r = tid - 262144;
        int l  = r & 63;
        int c  = (r >> 6) & 1;
        int ft = (r >> 7) & 3;
        int jt = (r >> 9) & 63;
        int b  = (r >> 15) & 3;

        int f  = ft * 16 + (l & 15);
        int j0 = jt * 64 + c * 32 + (l >> 4) * 8;
        const float2* s2 = (const float2*)V;

        S8 ar, ai;
        #pragma unroll
        for (int e = 0; e < 8; ++e) {
            float2 g = s2[(b * NN + j0 + e) * 64 + f];
            ar.u[e] = f2bf(g.x);
            ai.u[e] = f2bf(g.y);
        }
        int cid0 = (((b * 64 + jt) * 4 + ft) * 2 + c) * 2;
        *(bf16x8*)(VF + (cid0 + 0) * 512 + l * 8) = ar.v;
        *(bf16x8*)(VF + (cid0 + 1) * 512 + l * 8) = ai.v;
    } else if (tid < 393728) {                // ---- W_att frags ----
        int r = tid - 393216;
        int l  = r & 63;
        int c  = (r >> 6) & 1;
        int ft = r >> 7;
        int row = ft * 16 + (l & 15);
        int k0  = c * 32 + (l >> 4) * 8;
        const float* sp = W + row * 64 + k0;
        S8 a;
        #pragma unroll
        for (int e = 0; e < 8; ++e) a.u[e] = f2bf(sp[e]);
        *(bf16x8*)(WF + ((ft * 2 + c) * 64 + l) * 8) = a.v;
    } else {                                  // ---- zero d_out ----
        int r = tid - 393728;                 // 524288 float4's = 2M floats
        float4 zz = {0.f, 0.f, 0.f, 0.f};
        ((float4*)out)[r] = zz;
    }
}

// triangular inversion: largest it with it*(it+1)/2 <= g
__device__ __forceinline__ int tri_inv(int g) {
    int it = (int)((__builtin_sqrtf(8.0f * (float)g + 1.0f) - 1.0f) * 0.5f);
    while ((it + 1) * (it + 2) / 2 <= g) ++it;
    while (it * (it + 1) / 2 > g) --it;
    return it;
}

// ---------------------------------------------------------------------------
// Main kernel. 1040 blocks x 256 threads (4 waves). Each block processes
// exactly TSTEP=8 consecutive (it, jt) tile-steps of the flattened causal
// triangle of one batch -> near-perfect load balance. A block may straddle
// i-tile boundaries: loop over segments, per-segment Q load + epilogue.
// Wave w owns 16 query rows of the 64-row i-tile. Per j-tile:
//   S-phase: 32 mfma (complex QK^T), scale+leaky+causal, bf16 -> wave-private
//            LDS frag buffer (wave-synchronous; compiler orders LDS deps).
//   PV-phase: read W-frags, 16 mfma into per-segment O accumulators.
// Epilogue: O @ W_att^T + b_att; plain store if block owns whole i-tile,
// else fp32 atomicAdd (out pre-zeroed by prep_all).
// ---------------------------------------------------------------------------
__global__ __launch_bounds__(256, 4)
void attn_main(const short* __restrict__ QF, const short* __restrict__ KF,
               const short* __restrict__ VF, const short* __restrict__ WF,
               const float* __restrict__ batt, float* __restrict__ out) {
    __shared__ __align__(16) unsigned short wbuf[4][2048];  // 4KB per wave

    int bid = blockIdx.x;
    int b   = bid / BLKS_PER_B;
    int g   = (bid % BLKS_PER_B) * TSTEP;
    int gend = g + TSTEP;

    int w   = threadIdx.x >> 6;
    int l   = threadIdx.x & 63;
    int r16 = l & 15;
    int lb  = l >> 4;

    const f32x4 z = {0.f, 0.f, 0.f, 0.f};
    const float SCALE = 1.0f / 64.0f;   // 1/sqrt(4096)
    unsigned short* wb = wbuf[w];

    while (g < gend) {
        int it   = tri_inv(g);
        int base = it * (it + 1) / 2;
        int jt0  = g - base;
        int cnt  = min(gend - g, it + 1 - jt0);
        int jt1  = jt0 + cnt;

        // Q frags for this wave's 16 rows of i-tile `it`
        bf16x8 qf[2][2];
        {
            int rg = it * 4 + w;
            #pragma unroll
            for (int c = 0; c < 2; ++c)
                #pragma unroll
                for (int ch = 0; ch < 2; ++ch)
                    qf[c][ch] = *(const bf16x8*)(QF + (((b * 256 + rg) * 2 + c) * 2 + ch) * 512 + l * 8);
        }

        f32x4 o[4][2];
        #pragma unroll
        for (int ft = 0; ft < 4; ++ft) { o[ft][0] = z; o[ft][1] = z; }

        for (int jt = jt0; jt < jt1; ++jt) {
            bool diag = (jt == it);
            #pragma unroll
            for (int ct = 0; ct < 4; ++ct) {
                bf16x8 kf[2][2];
                int rg = jt * 4 + ct;
                #pragma unroll
                for (int c = 0; c < 2; ++c)
                    #pragma unroll
                    for (int ch = 0; ch < 2; ++ch)
                        kf[c][ch] = *(const bf16x8*)(KF + (((b * 256 + rg) * 2 + c) * 2 + ch) * 512 + l * 8);

                // sr = Qr.Kr^T - Qi.Ki^T ; si = Qr.Ki^T + Qi.Kr^T
                f32x4 t1 = __builtin_amdgcn_mfma_f32_16x16x32_bf16(qf[0][0], kf[0][0], z, 0, 0, 0);
                t1 = __builtin_amdgcn_mfma_f32_16x16x32_bf16(qf[1][0], kf[1][0], t1, 0, 0, 0);
                f32x4 t2 = __builtin_amdgcn_mfma_f32_16x16x32_bf16(qf[0][1], kf[0][1], z, 0, 0, 0);
                t2 = __builtin_amdgcn_mfma_f32_16x16x32_bf16(qf[1][1], kf[1][1], t2, 0, 0, 0);
                f32x4 si = __builtin_amdgcn_mfma_f32_16x16x32_bf16(qf[0][0], kf[0][1], z, 0, 0, 0);
                si = __builtin_amdgcn_mfma_f32_16x16x32_bf16(qf[1][0], kf[1][1], si, 0, 0, 0);
                si = __builtin_amdgcn_mfma_f32_16x16x32_bf16(qf[0][1], kf[0][0], si, 0, 0, 0);
                si = __builtin_amdgcn_mfma_f32_16x16x32_bf16(qf[1][1], kf[1][0], si, 0, 0, 0);

                // scatter w (bf16) into wave-private frag-major LDS buffer
                int cH  = ct >> 1;
                int lb2 = ((ct & 1) << 1) | (r16 >> 3);
                int e   = r16 & 7;
                int base_r = (cH * 2 + 0) * 512 + lb2 * 128 + lb * 32 + e;
                int base_i = (cH * 2 + 1) * 512 + lb2 * 128 + lb * 32 + e;
                #pragma unroll
                for (int reg = 0; reg < 4; ++reg) {
                    float sr = (t1[reg] - t2[reg]) * SCALE;
                    float sv = si[reg] * SCALE;
                    float wr = sr >= 0.f ? sr : 0.01f * sr;
                    float wi = sv >= 0.f ? sv : 0.01f * sv;
                    if (diag) {
                        int ig = w * 16 + lb * 4 + reg;
                        int jg = ct * 16 + r16;
                        if (jg > ig) { wr = 0.f; wi = 0.f; }
                    }
                    wb[base_r + reg * 8] = f2bf(wr);
                    wb[base_i + reg * 8] = f2bf(wi);
                }
            }

            bf16x8 wfr[2][2];
            #pragma unroll
            for (int c = 0; c < 2; ++c)
                #pragma unroll
                for (int ch = 0; ch < 2; ++ch)
                    wfr[c][ch] = *(const bf16x8*)(wb + (c * 2 + ch) * 512 + l * 8);

            // PV: O[i][f] += sum_j w[i][j] * V[j][f]  per channel
            #pragma unroll
            for (int ft = 0; ft < 4; ++ft) {
                #pragma unroll
                for (int ch = 0; ch < 2; ++ch) {
                    int cid0 = (((b * 64 + jt) * 4 + ft) * 2) * 2 + ch;
                    bf16x8 v0 = *(const bf16x8*)(VF + cid0 * 512 + l * 8);
                    bf16x8 v1 = *(const bf16x8*)(VF + (cid0 + 2) * 512 + l * 8);
                    o[ft][ch] = __builtin_amdgcn_mfma_f32_16x16x32_bf16(wfr[0][ch], v0, o[ft][ch], 0, 0, 0);
                    o[ft][ch] = __builtin_amdgcn_mfma_f32_16x16x32_bf16(wfr[1][ch], v1, o[ft][ch], 0, 0, 0);
                }
            }
        }

        // ---- epilogue for this segment: out += O @ W_att^T (+ b_att) ----
        #pragma unroll
        for (int ft = 0; ft < 4; ++ft) {
            int cH  = ft >> 1;
            int lb2 = ((ft & 1) << 1) | (r16 >> 3);
            int e   = r16 & 7;
            #pragma unroll
            for (int ch = 0; ch < 2; ++ch) {
                int bofs = (cH * 2 + ch) * 512 + lb2 * 128 + lb * 32 + e;
                #pragma unroll
                for (int reg = 0; reg < 4; ++reg)
                    wb[bofs + reg * 8] = f2bf(o[ft][ch][reg]);
            }
        }

        bf16x8 of[2][2];
        #pragma unroll
        for (int c = 0; c < 2; ++c)
            #pragma unroll
            for (int ch = 0; ch < 2; ++ch)
                of[c][ch] = *(const bf16x8*)(wb + (c * 2 + ch) * 512 + l * 8);

        bool whole = (jt0 == 0) && (jt1 == it + 1);
        bool addb  = (jt0 == 0);
        int ibase = b * NN + it * 64 + w * 16 + lb * 4;
        #pragma unroll
        for (int ft2 = 0; ft2 < 4; ++ft2) {
            bf16x8 wa0 = *(const bf16x8*)(WF + ((ft2 * 2 + 0) * 64 + l) * 8);
            bf16x8 wa1 = *(const bf16x8*)(WF + ((ft2 * 2 + 1) * 64 + l) * 8);
            float bb = addb ? batt[ft2 * 16 + r16] : 0.f;
            #pragma unroll
            for (int ch = 0; ch < 2; ++ch) {
                f32x4 acc = __builtin_amdgcn_mfma_f32_16x16x32_bf16(of[0][ch], wa0, z, 0, 0, 0);
                acc = __builtin_amdgcn_mfma_f32_16x16x32_bf16(of[1][ch], wa1, acc, 0, 0, 0);
                #pragma unroll
                for (int reg = 0; reg < 4; ++reg) {
                    int idx = ((ibase + reg) * 64 + ft2 * 16 + r16) * 2 + ch;
                    if (whole) out[idx] = acc[reg] + bb;
                    else       atomicAdd(out + idx, acc[reg] + bb);
                }
            }
        }

        g += cnt;
    }
}

// ---------------------------------------------------------------------------
extern "C" void kernel_launch(void* const* d_in, const int* in_sizes, int n_in,
                              void* d_out, int out_size, void* d_ws, size_t ws_size,
                              hipStream_t stream) {
    const float* Q  = (const float*)d_in[0];
    const float* K  = (const float*)d_in[1];
    const float* V  = (const float*)d_in[2];
    const float* W  = (const float*)d_in[3];
    const float* bA = (const float*)d_in[4];
    float* out = (float*)d_out;

    short* QF = (short*)d_ws;
    short* KF = QF + 2097152;
    short* VF = KF + 2097152;
    short* WF = VF + 2097152;

    prep_all<<<3586, 256, 0, stream>>>(Q, K, V, W, QF, KF, VF, WF, out);
    attn_main<<<NB * BLKS_PER_B, 256, 0, stream>>>(QF, KF, VF, WF, bA, out);
}